// Round 7
// baseline (942.174 us; speedup 1.0000x reference)
//
#include <hip/hip_runtime.h>
#include <math.h>

// CrossModalAttentionFusion: B=262144, D=32, 3 tokens, 4 heads. f32 in/out.
// R6 post-mortem: heavy kernel latency-bound on s_load weight operands
// (VALUBusy 28%, occ 8.9%, 271us vs ~20us VALU floor). R7: weights staged in
// LDS (ds_read_b128, wave-uniform broadcast), per-head dataflow restructured
// (Q regs -> K-stream scores -> softmax -> V-stream with folded out-proj via
// pre-transposed Wout) to kill kk/vv/ctx arrays; detect+classify+light fused
// into one kernel with block-local mask-encoding detection.

#define NEGV (-1e9f)
#define LN_EPS 1e-5f
typedef unsigned int  u32;
typedef unsigned char u8;
typedef unsigned long long u64;

// ---------------- classify + light (fused, self-detecting) ----------------
// Block bi detects encoding from the byte-region words [192*bi, 192*bi+192)
// (valid under both encodings; if byte-packed, P(all words<=1) = 8^-192 ~ 0).
// Heavy samples -> compacted list (1 atomic per wave); light handled inline.
__global__ __launch_bounds__(256) void cmaf_classify_light(
    const u32* __restrict__ mwords,
    u32* __restrict__ cnt,            // [0]=heavy count (pre-zeroed)
    u32* __restrict__ heavyList,
    const float* __restrict__ metric, const float* __restrict__ logx,
    const float* __restrict__ trace, float* __restrict__ out,
    int B, int nwords)
{
    __shared__ u32 sFlag;
    const int t  = threadIdx.x;
    const int bi = blockIdx.x;
    if (t == 0) sFlag = 0;
    __syncthreads();
    {
        int widx = bi * 192 + (t % 192);
        if (widx >= nwords) widx = nwords - 1;
        if (mwords[widx] > 1u) sFlag = 1u;   // racy all-write-1: fine
    }
    __syncthreads();
    const bool bytePacked = (sFlag != 0);

    const int i = bi * 256 + t;
    bool m0 = false, m1 = false, m2 = false;
    if (i < B) {
        if (bytePacked) {
            const u8* mb = (const u8*)mwords;
            m0 = mb[3*i+0] != 0; m1 = mb[3*i+1] != 0; m2 = mb[3*i+2] != 0;
        } else {
            const int* mi = (const int*)mwords;
            m0 = mi[3*i+0] != 0; m1 = mi[3*i+1] != 0; m2 = mi[3*i+2] != 0;
        }
    }
    const bool heavy = (i < B) && (((int)m0 + (int)m1 + (int)m2) >= 2);

    const int lane = t & 63;
    const u64 hb = __ballot(heavy);
    u32 hbase = 0;
    if (lane == 0) hbase = atomicAdd(&cnt[0], (u32)__popcll(hb));
    hbase = __shfl(hbase, 0, 64);
    const u64 below = (lane == 63) ? (hb & 0x7fffffffffffffffull)
                                   : (hb & ((1ull << lane) - 1ull));
    if (heavy) {
        heavyList[hbase + __popcll(below)] =
            (u32)i | ((u32)m0 << 24) | ((u32)m1 << 25) | ((u32)m2 << 26);
    } else if (i < B) {
        // light path: count<=1 -> single available row (or zeros)
        const float* src = m0 ? metric : (m1 ? logx : (m2 ? trace : nullptr));
        float4* po = reinterpret_cast<float4*>(out + (size_t)i*32);
        if (src) {
            const float4* ps = reinterpret_cast<const float4*>(src + (size_t)i*32);
            #pragma unroll
            for (int k = 0; k < 8; ++k) po[k] = ps[k];
        } else {
            float4 z; z.x = z.y = z.z = z.w = 0.f;
            #pragma unroll
            for (int k = 0; k < 8; ++k) po[k] = z;
        }
    }
}

// ---------------- heavy kernel: LDS-staged weights ----------------
__global__ __launch_bounds__(256, 2) void cmaf_heavy(
    const u32* __restrict__ list, const u32* __restrict__ cnt,
    const float* __restrict__ metric, const float* __restrict__ logx,
    const float* __restrict__ trace,
    const float* __restrict__ Win, const float* __restrict__ bin,
    const float* __restrict__ Wout, const float* __restrict__ bout,
    const float* __restrict__ mw, const float* __restrict__ gam,
    const float* __restrict__ bet, float* __restrict__ out)
{
    __shared__ float sWin[96*32];    // [row r][j]
    __shared__ float sWoutT[32*32];  // [k][o] = Wout[o][k]
    __shared__ float sBin[96];
    __shared__ float sBout[32], sGam[32], sBet[32], sMw[4];

    const int t = threadIdx.x;
    for (int idx = t; idx < 96*32; idx += 256) sWin[idx] = Win[idx];
    for (int idx = t; idx < 32*32; idx += 256) {
        int o = idx >> 5, k = idx & 31;
        sWoutT[k*32 + o] = Wout[idx];          // coalesced read, transposed write
    }
    if (t < 96) sBin[t] = bin[t];
    if (t < 32) { sBout[t] = bout[t]; sGam[t] = gam[t]; sBet[t] = bet[t]; }
    if (t < 3)  sMw[t] = mw[t];
    __syncthreads();

    const u32 n = cnt[0];
    const u32 i = blockIdx.x * 256 + t;
    if (i >= n) return;
    const u32 e = list[i];
    const int b = (int)(e & 0xFFFFFFu);
    const bool m0 = (e >> 24) & 1u, m1 = (e >> 25) & 1u, m2 = (e >> 26) & 1u;

    const float4* W4  = reinterpret_cast<const float4*>(sWin);
    const float4* WT4 = reinterpret_cast<const float4*>(sWoutT);

    // ---- features ----
    float f[3][32];
    {
        const float4* p0 = reinterpret_cast<const float4*>(metric + (size_t)b*32);
        const float4* p1 = reinterpret_cast<const float4*>(logx   + (size_t)b*32);
        const float4* p2 = reinterpret_cast<const float4*>(trace  + (size_t)b*32);
        #pragma unroll
        for (int q = 0; q < 8; ++q) {
            float4 a = p0[q];
            f[0][4*q+0]=a.x; f[0][4*q+1]=a.y; f[0][4*q+2]=a.z; f[0][4*q+3]=a.w;
            float4 c = p1[q];
            f[1][4*q+0]=c.x; f[1][4*q+1]=c.y; f[1][4*q+2]=c.z; f[1][4*q+3]=c.w;
            float4 d = p2[q];
            f[2][4*q+0]=d.x; f[2][4*q+1]=d.y; f[2][4*q+2]=d.z; f[2][4*q+3]=d.w;
        }
    }

    // ---- modal-weight softmax ----
    float w0, w1, w2;
    {
        float l0 = m0 ? sMw[0] : NEGV;
        float l1 = m1 ? sMw[1] : NEGV;
        float l2 = m2 ? sMw[2] : NEGV;
        float mx = fmaxf(l0, fmaxf(l1, l2));
        float e0 = __expf(l0 - mx), e1 = __expf(l1 - mx), e2 = __expf(l2 - mx);
        float inv = 1.f / (e0 + e1 + e2);
        w0 = e0*inv; w1 = e1*inv; w2 = e2*inv;
    }

    float acc[3][32];
    #pragma unroll
    for (int s = 0; s < 3; ++s)
        #pragma unroll
        for (int o = 0; o < 32; ++o) acc[s][o] = 0.f;

    const float scale = 0.35355339059327373f;  // 1/sqrt(8)

    #pragma unroll 1
    for (int h = 0; h < 4; ++h) {
        // ---- Q[3][8] ----
        float q0[8], q1[8], q2[8];
        #pragma unroll
        for (int d = 0; d < 8; ++d) {
            const int r = h*8 + d;
            float a0 = sBin[r], a1 = a0, a2 = a0;
            #pragma unroll
            for (int jj = 0; jj < 8; ++jj) {
                float4 w = W4[r*8 + jj];
                a0 = fmaf(f[0][4*jj+0], w.x, a0); a0 = fmaf(f[0][4*jj+1], w.y, a0);
                a0 = fmaf(f[0][4*jj+2], w.z, a0); a0 = fmaf(f[0][4*jj+3], w.w, a0);
                a1 = fmaf(f[1][4*jj+0], w.x, a1); a1 = fmaf(f[1][4*jj+1], w.y, a1);
                a1 = fmaf(f[1][4*jj+2], w.z, a1); a1 = fmaf(f[1][4*jj+3], w.w, a1);
                a2 = fmaf(f[2][4*jj+0], w.x, a2); a2 = fmaf(f[2][4*jj+1], w.y, a2);
                a2 = fmaf(f[2][4*jj+2], w.z, a2); a2 = fmaf(f[2][4*jj+3], w.w, a2);
            }
            q0[d] = a0; q1[d] = a1; q2[d] = a2;
        }
        // ---- K streaming -> scores sc[sq][ktok] ----
        float sc[3][3];
        #pragma unroll
        for (int a = 0; a < 3; ++a)
            #pragma unroll
            for (int c = 0; c < 3; ++c) sc[a][c] = 0.f;
        #pragma unroll
        for (int d = 0; d < 8; ++d) {
            const int r = 32 + h*8 + d;
            float k0 = sBin[r], k1 = k0, k2 = k0;
            #pragma unroll
            for (int jj = 0; jj < 8; ++jj) {
                float4 w = W4[r*8 + jj];
                k0 = fmaf(f[0][4*jj+0], w.x, k0); k0 = fmaf(f[0][4*jj+1], w.y, k0);
                k0 = fmaf(f[0][4*jj+2], w.z, k0); k0 = fmaf(f[0][4*jj+3], w.w, k0);
                k1 = fmaf(f[1][4*jj+0], w.x, k1); k1 = fmaf(f[1][4*jj+1], w.y, k1);
                k1 = fmaf(f[1][4*jj+2], w.z, k1); k1 = fmaf(f[1][4*jj+3], w.w, k1);
                k2 = fmaf(f[2][4*jj+0], w.x, k2); k2 = fmaf(f[2][4*jj+1], w.y, k2);
                k2 = fmaf(f[2][4*jj+2], w.z, k2); k2 = fmaf(f[2][4*jj+3], w.w, k2);
            }
            sc[0][0] = fmaf(q0[d], k0, sc[0][0]);
            sc[0][1] = fmaf(q0[d], k1, sc[0][1]);
            sc[0][2] = fmaf(q0[d], k2, sc[0][2]);
            sc[1][0] = fmaf(q1[d], k0, sc[1][0]);
            sc[1][1] = fmaf(q1[d], k1, sc[1][1]);
            sc[1][2] = fmaf(q1[d], k2, sc[1][2]);
            sc[2][0] = fmaf(q2[d], k0, sc[2][0]);
            sc[2][1] = fmaf(q2[d], k1, sc[2][1]);
            sc[2][2] = fmaf(q2[d], k2, sc[2][2]);
        }
        // ---- mask + softmax -> p[sq][ktok] ----
        float p[3][3];
        #pragma unroll
        for (int sq = 0; sq < 3; ++sq) {
            float s0 = m0 ? sc[sq][0]*scale : NEGV;
            float s1 = m1 ? sc[sq][1]*scale : NEGV;
            float s2 = m2 ? sc[sq][2]*scale : NEGV;
            float mx = fmaxf(s0, fmaxf(s1, s2));
            float e0 = __expf(s0 - mx), e1 = __expf(s1 - mx), e2 = __expf(s2 - mx);
            float inv = 1.f / (e0 + e1 + e2);
            p[sq][0] = e0*inv; p[sq][1] = e1*inv; p[sq][2] = e2*inv;
        }
        // ---- V streaming -> ctx (transient) -> out-proj fold ----
        #pragma unroll
        for (int d = 0; d < 8; ++d) {
            const int r = 64 + h*8 + d;
            float v0 = sBin[r], v1 = v0, v2 = v0;
            #pragma unroll
            for (int jj = 0; jj < 8; ++jj) {
                float4 w = W4[r*8 + jj];
                v0 = fmaf(f[0][4*jj+0], w.x, v0); v0 = fmaf(f[0][4*jj+1], w.y, v0);
                v0 = fmaf(f[0][4*jj+2], w.z, v0); v0 = fmaf(f[0][4*jj+3], w.w, v0);
                v1 = fmaf(f[1][4*jj+0], w.x, v1); v1 = fmaf(f[1][4*jj+1], w.y, v1);
                v1 = fmaf(f[1][4*jj+2], w.z, v1); v1 = fmaf(f[1][4*jj+3], w.w, v1);
                v2 = fmaf(f[2][4*jj+0], w.x, v2); v2 = fmaf(f[2][4*jj+1], w.y, v2);
                v2 = fmaf(f[2][4*jj+2], w.z, v2); v2 = fmaf(f[2][4*jj+3], w.w, v2);
            }
            float c0 = p[0][0]*v0 + p[0][1]*v1 + p[0][2]*v2;
            float c1 = p[1][0]*v0 + p[1][1]*v1 + p[1][2]*v2;
            float c2 = p[2][0]*v0 + p[2][1]*v1 + p[2][2]*v2;
            #pragma unroll
            for (int oo = 0; oo < 8; ++oo) {
                float4 w = WT4[(h*8 + d)*8 + oo];
                acc[0][4*oo+0] = fmaf(c0, w.x, acc[0][4*oo+0]);
                acc[0][4*oo+1] = fmaf(c0, w.y, acc[0][4*oo+1]);
                acc[0][4*oo+2] = fmaf(c0, w.z, acc[0][4*oo+2]);
                acc[0][4*oo+3] = fmaf(c0, w.w, acc[0][4*oo+3]);
                acc[1][4*oo+0] = fmaf(c1, w.x, acc[1][4*oo+0]);
                acc[1][4*oo+1] = fmaf(c1, w.y, acc[1][4*oo+1]);
                acc[1][4*oo+2] = fmaf(c1, w.z, acc[1][4*oo+2]);
                acc[1][4*oo+3] = fmaf(c1, w.w, acc[1][4*oo+3]);
                acc[2][4*oo+0] = fmaf(c2, w.x, acc[2][4*oo+0]);
                acc[2][4*oo+1] = fmaf(c2, w.y, acc[2][4*oo+1]);
                acc[2][4*oo+2] = fmaf(c2, w.z, acc[2][4*oo+2]);
                acc[2][4*oo+3] = fmaf(c2, w.w, acc[2][4*oo+3]);
            }
        }
    }

    // ---- epilogue: weighted residual + LayerNorm + weighted sum ----
    float fused[32];
    #pragma unroll
    for (int o = 0; o < 32; ++o) fused[o] = 0.f;

    #pragma unroll
    for (int s = 0; s < 3; ++s) {
        const float ws = (s == 0) ? w0 : (s == 1) ? w1 : w2;
        float row[32];
        float mu = 0.f;
        #pragma unroll
        for (int o = 0; o < 32; ++o) {
            float a = acc[s][o] + sBout[o];
            row[o] = fmaf(a, ws, f[s][o]);
            mu += row[o];
        }
        mu *= (1.f/32.f);
        float var = 0.f;
        #pragma unroll
        for (int o = 0; o < 32; ++o) { float d = row[o] - mu; var = fmaf(d, d, var); }
        var *= (1.f/32.f);
        const float rs = rsqrtf(var + LN_EPS);
        #pragma unroll
        for (int o = 0; o < 32; ++o) {
            float y = (row[o] - mu) * rs * sGam[o] + sBet[o];
            fused[o] = fmaf(ws, y, fused[o]);
        }
    }

    float4* po = reinterpret_cast<float4*>(out + (size_t)b*32);
    #pragma unroll
    for (int q = 0; q < 8; ++q) {
        float4 r;
        r.x = fused[4*q+0]; r.y = fused[4*q+1]; r.z = fused[4*q+2]; r.w = fused[4*q+3];
        po[q] = r;
    }
}

// ---------------- fallback (ws too small): monolithic, self-detecting ----------------
__global__ __launch_bounds__(256, 2) void cmaf_mono(
    const u32* __restrict__ mwords,
    const float* __restrict__ metric, const float* __restrict__ logx,
    const float* __restrict__ trace,
    const float* __restrict__ Win, const float* __restrict__ bin,
    const float* __restrict__ Wout, const float* __restrict__ bout,
    const float* __restrict__ mw, const float* __restrict__ gam,
    const float* __restrict__ bet, float* __restrict__ out, int B, int nwords)
{
    __shared__ u32 sFlag;
    if (threadIdx.x == 0) sFlag = 0;
    __syncthreads();
    {
        int widx = blockIdx.x * 192 + (threadIdx.x % 192);
        if (widx >= nwords) widx = nwords - 1;
        if (mwords[widx] > 1u) sFlag = 1u;
    }
    __syncthreads();
    const bool bytePacked = (sFlag != 0);
    int b = blockIdx.x * 256 + threadIdx.x;
    if (b >= B) return;
    bool m0, m1, m2;
    if (bytePacked) {
        const u8* mb = (const u8*)mwords;
        m0 = mb[3*b+0] != 0; m1 = mb[3*b+1] != 0; m2 = mb[3*b+2] != 0;
    } else {
        const int* mi = (const int*)mwords;
        m0 = mi[3*b+0] != 0; m1 = mi[3*b+1] != 0; m2 = mi[3*b+2] != 0;
    }
    const int count = (int)m0 + (int)m1 + (int)m2;
    float4* po = reinterpret_cast<float4*>(out + (size_t)b*32);
    if (count <= 1) {
        const float* src = m0 ? metric : (m1 ? logx : (m2 ? trace : nullptr));
        if (src) {
            const float4* ps = reinterpret_cast<const float4*>(src + (size_t)b*32);
            #pragma unroll
            for (int k = 0; k < 8; ++k) po[k] = ps[k];
        } else {
            float4 z; z.x = z.y = z.z = z.w = 0.f;
            #pragma unroll
            for (int k = 0; k < 8; ++k) po[k] = z;
        }
        return;
    }
    // slow-but-correct heavy path (global weights) — fallback only
    float f[3][32];
    const float4* p0 = reinterpret_cast<const float4*>(metric + (size_t)b*32);
    const float4* p1 = reinterpret_cast<const float4*>(logx   + (size_t)b*32);
    const float4* p2 = reinterpret_cast<const float4*>(trace  + (size_t)b*32);
    #pragma unroll
    for (int q = 0; q < 8; ++q) {
        float4 a = p0[q];
        f[0][4*q+0]=a.x; f[0][4*q+1]=a.y; f[0][4*q+2]=a.z; f[0][4*q+3]=a.w;
        float4 c = p1[q];
        f[1][4*q+0]=c.x; f[1][4*q+1]=c.y; f[1][4*q+2]=c.z; f[1][4*q+3]=c.w;
        float4 d = p2[q];
        f[2][4*q+0]=d.x; f[2][4*q+1]=d.y; f[2][4*q+2]=d.z; f[2][4*q+3]=d.w;
    }
    float w0, w1, w2;
    {
        float l0 = m0 ? mw[0] : NEGV;
        float l1 = m1 ? mw[1] : NEGV;
        float l2 = m2 ? mw[2] : NEGV;
        float mx = fmaxf(l0, fmaxf(l1, l2));
        float e0 = __expf(l0 - mx), e1 = __expf(l1 - mx), e2 = __expf(l2 - mx);
        float inv = 1.f / (e0 + e1 + e2);
        w0 = e0*inv; w1 = e1*inv; w2 = e2*inv;
    }
    float acc[3][32];
    #pragma unroll
    for (int s = 0; s < 3; ++s)
        #pragma unroll
        for (int o = 0; o < 32; ++o) acc[s][o] = 0.f;
    const float scale = 0.35355339059327373f;
    #pragma unroll 1
    for (int h = 0; h < 4; ++h) {
        float kk[3][8], vv[3][8];
        #pragma unroll
        for (int s = 0; s < 3; ++s)
            #pragma unroll
            for (int d = 0; d < 8; ++d) {
                const int r = h*8 + d;
                float ak = bin[32 + r], av = bin[64 + r];
                const float* wkr = Win + (size_t)(32 + r)*32;
                const float* wvr = Win + (size_t)(64 + r)*32;
                #pragma unroll
                for (int j = 0; j < 32; ++j) {
                    float x = f[s][j];
                    ak = fmaf(x, wkr[j], ak); av = fmaf(x, wvr[j], av);
                }
                kk[s][d] = ak; vv[s][d] = av;
            }
        #pragma unroll
        for (int sq = 0; sq < 3; ++sq) {
            float s0 = 0.f, s1 = 0.f, s2 = 0.f;
            #pragma unroll
            for (int d = 0; d < 8; ++d) {
                const int r = h*8 + d;
                float aq = bin[r];
                const float* wqr = Win + (size_t)r*32;
                #pragma unroll
                for (int j = 0; j < 32; ++j) aq = fmaf(f[sq][j], wqr[j], aq);
                s0 = fmaf(aq, kk[0][d], s0);
                s1 = fmaf(aq, kk[1][d], s1);
                s2 = fmaf(aq, kk[2][d], s2);
            }
            s0 = m0 ? s0*scale : NEGV;
            s1 = m1 ? s1*scale : NEGV;
            s2 = m2 ? s2*scale : NEGV;
            float mx = fmaxf(s0, fmaxf(s1, s2));
            float e0 = __expf(s0 - mx), e1 = __expf(s1 - mx), e2 = __expf(s2 - mx);
            float inv = 1.f / (e0 + e1 + e2);
            e0 *= inv; e1 *= inv; e2 *= inv;
            #pragma unroll
            for (int d = 0; d < 8; ++d) {
                float c = e0*vv[0][d] + e1*vv[1][d] + e2*vv[2][d];
                const float* wc = Wout + h*8 + d;
                #pragma unroll
                for (int o = 0; o < 32; ++o)
                    acc[sq][o] = fmaf(c, wc[(size_t)o*32], acc[sq][o]);
            }
        }
    }
    float fused[32];
    #pragma unroll
    for (int o = 0; o < 32; ++o) fused[o] = 0.f;
    #pragma unroll
    for (int s = 0; s < 3; ++s) {
        const float ws = (s == 0) ? w0 : (s == 1) ? w1 : w2;
        float row[32];
        float mu = 0.f;
        #pragma unroll
        for (int o = 0; o < 32; ++o) {
            float a = acc[s][o] + bout[o];
            row[o] = fmaf(a, ws, f[s][o]);
            mu += row[o];
        }
        mu *= (1.f/32.f);
        float var = 0.f;
        #pragma unroll
        for (int o = 0; o < 32; ++o) { float d = row[o] - mu; var = fmaf(d, d, var); }
        var *= (1.f/32.f);
        const float rs = rsqrtf(var + LN_EPS);
        #pragma unroll
        for (int o = 0; o < 32; ++o) {
            float y = (row[o] - mu) * rs * gam[o] + bet[o];
            fused[o] = fmaf(ws, y, fused[o]);
        }
    }
    #pragma unroll
    for (int q = 0; q < 8; ++q) {
        float4 r;
        r.x = fused[4*q+0]; r.y = fused[4*q+1]; r.z = fused[4*q+2]; r.w = fused[4*q+3];
        po[q] = r;
    }
}

extern "C" void kernel_launch(void* const* d_in, const int* in_sizes, int n_in,
                              void* d_out, int out_size, void* d_ws, size_t ws_size,
                              hipStream_t stream) {
    const float* metric = (const float*)d_in[0];
    const float* logx   = (const float*)d_in[1];
    const float* trace  = (const float*)d_in[2];
    const u32*   masks  = (const u32*)d_in[3];
    const float* Win    = (const float*)d_in[4];
    const float* bin    = (const float*)d_in[5];
    const float* Wout   = (const float*)d_in[6];
    const float* bout   = (const float*)d_in[7];
    const float* mw     = (const float*)d_in[8];
    const float* gam    = (const float*)d_in[9];
    const float* bet    = (const float*)d_in[10];
    float* out = (float*)d_out;

    const int B = in_sizes[0] / 32;         // 262144
    const int grid = (B + 255) / 256;
    const int nwords = (3 * B) / 4;         // valid word count in byte encoding

    u32* ws        = (u32*)d_ws;
    u32* cnt       = ws;                    // [0]
    u32* heavyList = ws + 4;                // [4, 4+B)
    const size_t need = (size_t)(4 + (size_t)B) * 4;

    if (ws_size >= need) {
        hipMemsetAsync(d_ws, 0, 16, stream);
        hipLaunchKernelGGL(cmaf_classify_light, dim3(grid), dim3(256), 0, stream,
                           masks, cnt, heavyList, metric, logx, trace, out,
                           B, nwords);
        hipLaunchKernelGGL(cmaf_heavy, dim3(grid), dim3(256), 0, stream,
                           heavyList, cnt, metric, logx, trace,
                           Win, bin, Wout, bout, mw, gam, bet, out);
    } else {
        hipLaunchKernelGGL(cmaf_mono, dim3(grid), dim3(256), 0, stream,
                           masks, metric, logx, trace,
                           Win, bin, Wout, bout, mw, gam, bet, out, B, nwords);
    }
}

// Round 8
// 577.932 us; speedup vs baseline: 1.6302x; 1.6302x over previous
//
#include <hip/hip_runtime.h>
#include <math.h>

// CrossModalAttentionFusion: B=262144, D=32, 3 tokens, 4 heads. f32 in/out.
// R7 post-mortem: accidental __launch_bounds__(256,2) re-capped VGPR at 128
// -> 2.4GB scratch spill traffic (FETCH 952MB/WRITE 1447MB), VALUBusy 4.8%.
// R8: same structure, launch_bounds(256,1) so the ~250-reg live set stays in
// VGPRs (R5 established 216-VGPR no-spill at this bound).

#define NEGV (-1e9f)
#define LN_EPS 1e-5f
typedef unsigned int  u32;
typedef unsigned char u8;
typedef unsigned long long u64;

// ---------------- classify + light (fused, self-detecting) ----------------
// Block bi detects mask encoding from words [192*bi, 192*bi+192) of the
// byte-sized region (valid under both encodings; byte-packed data has a >1
// word with probability 1-8^-192). Heavy samples -> compacted list (1 atomic
// per wave); light samples handled inline (copy/zeros).
__global__ __launch_bounds__(256) void cmaf_classify_light(
    const u32* __restrict__ mwords,
    u32* __restrict__ cnt,            // [0]=heavy count (pre-zeroed)
    u32* __restrict__ heavyList,
    const float* __restrict__ metric, const float* __restrict__ logx,
    const float* __restrict__ trace, float* __restrict__ out,
    int B, int nwords)
{
    __shared__ u32 sFlag;
    const int t  = threadIdx.x;
    const int bi = blockIdx.x;
    if (t == 0) sFlag = 0;
    __syncthreads();
    {
        int widx = bi * 192 + (t % 192);
        if (widx >= nwords) widx = nwords - 1;
        if (mwords[widx] > 1u) sFlag = 1u;   // racy all-write-1: fine
    }
    __syncthreads();
    const bool bytePacked = (sFlag != 0);

    const int i = bi * 256 + t;
    bool m0 = false, m1 = false, m2 = false;
    if (i < B) {
        if (bytePacked) {
            const u8* mb = (const u8*)mwords;
            m0 = mb[3*i+0] != 0; m1 = mb[3*i+1] != 0; m2 = mb[3*i+2] != 0;
        } else {
            const int* mi = (const int*)mwords;
            m0 = mi[3*i+0] != 0; m1 = mi[3*i+1] != 0; m2 = mi[3*i+2] != 0;
        }
    }
    const bool heavy = (i < B) && (((int)m0 + (int)m1 + (int)m2) >= 2);

    const int lane = t & 63;
    const u64 hb = __ballot(heavy);
    u32 hbase = 0;
    if (lane == 0) hbase = atomicAdd(&cnt[0], (u32)__popcll(hb));
    hbase = __shfl(hbase, 0, 64);
    const u64 below = (lane == 63) ? (hb & 0x7fffffffffffffffull)
                                   : (hb & ((1ull << lane) - 1ull));
    if (heavy) {
        heavyList[hbase + __popcll(below)] =
            (u32)i | ((u32)m0 << 24) | ((u32)m1 << 25) | ((u32)m2 << 26);
    } else if (i < B) {
        const float* src = m0 ? metric : (m1 ? logx : (m2 ? trace : nullptr));
        float4* po = reinterpret_cast<float4*>(out + (size_t)i*32);
        if (src) {
            const float4* ps = reinterpret_cast<const float4*>(src + (size_t)i*32);
            #pragma unroll
            for (int k = 0; k < 8; ++k) po[k] = ps[k];
        } else {
            float4 z; z.x = z.y = z.z = z.w = 0.f;
            #pragma unroll
            for (int k = 0; k < 8; ++k) po[k] = z;
        }
    }
}

// ---------------- heavy kernel: LDS-staged weights, no spills ----------------
__global__ __launch_bounds__(256, 1) void cmaf_heavy(
    const u32* __restrict__ list, const u32* __restrict__ cnt,
    const float* __restrict__ metric, const float* __restrict__ logx,
    const float* __restrict__ trace,
    const float* __restrict__ Win, const float* __restrict__ bin,
    const float* __restrict__ Wout, const float* __restrict__ bout,
    const float* __restrict__ mw, const float* __restrict__ gam,
    const float* __restrict__ bet, float* __restrict__ out)
{
    __shared__ float sWin[96*32];    // [row r][j]
    __shared__ float sWoutT[32*32];  // [k][o] = Wout[o][k]
    __shared__ float sBin[96];
    __shared__ float sBout[32], sGam[32], sBet[32], sMw[4];

    const int t = threadIdx.x;
    for (int idx = t; idx < 96*32; idx += 256) sWin[idx] = Win[idx];
    for (int idx = t; idx < 32*32; idx += 256) {
        int o = idx >> 5, k = idx & 31;
        sWoutT[k*32 + o] = Wout[idx];          // coalesced read, transposed write
    }
    if (t < 96) sBin[t] = bin[t];
    if (t < 32) { sBout[t] = bout[t]; sGam[t] = gam[t]; sBet[t] = bet[t]; }
    if (t < 3)  sMw[t] = mw[t];
    __syncthreads();

    const u32 n = cnt[0];
    const u32 i = blockIdx.x * 256 + t;
    if (i >= n) return;
    const u32 e = list[i];
    const int b = (int)(e & 0xFFFFFFu);
    const bool m0 = (e >> 24) & 1u, m1 = (e >> 25) & 1u, m2 = (e >> 26) & 1u;

    const float4* W4  = reinterpret_cast<const float4*>(sWin);
    const float4* WT4 = reinterpret_cast<const float4*>(sWoutT);

    // ---- features ----
    float f[3][32];
    {
        const float4* p0 = reinterpret_cast<const float4*>(metric + (size_t)b*32);
        const float4* p1 = reinterpret_cast<const float4*>(logx   + (size_t)b*32);
        const float4* p2 = reinterpret_cast<const float4*>(trace  + (size_t)b*32);
        #pragma unroll
        for (int q = 0; q < 8; ++q) {
            float4 a = p0[q];
            f[0][4*q+0]=a.x; f[0][4*q+1]=a.y; f[0][4*q+2]=a.z; f[0][4*q+3]=a.w;
            float4 c = p1[q];
            f[1][4*q+0]=c.x; f[1][4*q+1]=c.y; f[1][4*q+2]=c.z; f[1][4*q+3]=c.w;
            float4 d = p2[q];
            f[2][4*q+0]=d.x; f[2][4*q+1]=d.y; f[2][4*q+2]=d.z; f[2][4*q+3]=d.w;
        }
    }

    // ---- modal-weight softmax ----
    float w0, w1, w2;
    {
        float l0 = m0 ? sMw[0] : NEGV;
        float l1 = m1 ? sMw[1] : NEGV;
        float l2 = m2 ? sMw[2] : NEGV;
        float mx = fmaxf(l0, fmaxf(l1, l2));
        float e0 = __expf(l0 - mx), e1 = __expf(l1 - mx), e2 = __expf(l2 - mx);
        float inv = 1.f / (e0 + e1 + e2);
        w0 = e0*inv; w1 = e1*inv; w2 = e2*inv;
    }

    float acc[3][32];
    #pragma unroll
    for (int s = 0; s < 3; ++s)
        #pragma unroll
        for (int o = 0; o < 32; ++o) acc[s][o] = 0.f;

    const float scale = 0.35355339059327373f;  // 1/sqrt(8)

    #pragma unroll 1
    for (int h = 0; h < 4; ++h) {
        // ---- Q[3][8] ----
        float q0[8], q1[8], q2[8];
        #pragma unroll
        for (int d = 0; d < 8; ++d) {
            const int r = h*8 + d;
            float a0 = sBin[r], a1 = a0, a2 = a0;
            #pragma unroll
            for (int jj = 0; jj < 8; ++jj) {
                float4 w = W4[r*8 + jj];
                a0 = fmaf(f[0][4*jj+0], w.x, a0); a0 = fmaf(f[0][4*jj+1], w.y, a0);
                a0 = fmaf(f[0][4*jj+2], w.z, a0); a0 = fmaf(f[0][4*jj+3], w.w, a0);
                a1 = fmaf(f[1][4*jj+0], w.x, a1); a1 = fmaf(f[1][4*jj+1], w.y, a1);
                a1 = fmaf(f[1][4*jj+2], w.z, a1); a1 = fmaf(f[1][4*jj+3], w.w, a1);
                a2 = fmaf(f[2][4*jj+0], w.x, a2); a2 = fmaf(f[2][4*jj+1], w.y, a2);
                a2 = fmaf(f[2][4*jj+2], w.z, a2); a2 = fmaf(f[2][4*jj+3], w.w, a2);
            }
            q0[d] = a0; q1[d] = a1; q2[d] = a2;
        }
        // ---- K streaming -> scores ----
        float sc[3][3];
        #pragma unroll
        for (int a = 0; a < 3; ++a)
            #pragma unroll
            for (int c = 0; c < 3; ++c) sc[a][c] = 0.f;
        #pragma unroll
        for (int d = 0; d < 8; ++d) {
            const int r = 32 + h*8 + d;
            float k0 = sBin[r], k1 = k0, k2 = k0;
            #pragma unroll
            for (int jj = 0; jj < 8; ++jj) {
                float4 w = W4[r*8 + jj];
                k0 = fmaf(f[0][4*jj+0], w.x, k0); k0 = fmaf(f[0][4*jj+1], w.y, k0);
                k0 = fmaf(f[0][4*jj+2], w.z, k0); k0 = fmaf(f[0][4*jj+3], w.w, k0);
                k1 = fmaf(f[1][4*jj+0], w.x, k1); k1 = fmaf(f[1][4*jj+1], w.y, k1);
                k1 = fmaf(f[1][4*jj+2], w.z, k1); k1 = fmaf(f[1][4*jj+3], w.w, k1);
                k2 = fmaf(f[2][4*jj+0], w.x, k2); k2 = fmaf(f[2][4*jj+1], w.y, k2);
                k2 = fmaf(f[2][4*jj+2], w.z, k2); k2 = fmaf(f[2][4*jj+3], w.w, k2);
            }
            sc[0][0] = fmaf(q0[d], k0, sc[0][0]);
            sc[0][1] = fmaf(q0[d], k1, sc[0][1]);
            sc[0][2] = fmaf(q0[d], k2, sc[0][2]);
            sc[1][0] = fmaf(q1[d], k0, sc[1][0]);
            sc[1][1] = fmaf(q1[d], k1, sc[1][1]);
            sc[1][2] = fmaf(q1[d], k2, sc[1][2]);
            sc[2][0] = fmaf(q2[d], k0, sc[2][0]);
            sc[2][1] = fmaf(q2[d], k1, sc[2][1]);
            sc[2][2] = fmaf(q2[d], k2, sc[2][2]);
        }
        // ---- mask + softmax ----
        float p[3][3];
        #pragma unroll
        for (int sq = 0; sq < 3; ++sq) {
            float s0 = m0 ? sc[sq][0]*scale : NEGV;
            float s1 = m1 ? sc[sq][1]*scale : NEGV;
            float s2 = m2 ? sc[sq][2]*scale : NEGV;
            float mx = fmaxf(s0, fmaxf(s1, s2));
            float e0 = __expf(s0 - mx), e1 = __expf(s1 - mx), e2 = __expf(s2 - mx);
            float inv = 1.f / (e0 + e1 + e2);
            p[sq][0] = e0*inv; p[sq][1] = e1*inv; p[sq][2] = e2*inv;
        }
        // ---- V streaming -> ctx -> out-proj fold ----
        #pragma unroll
        for (int d = 0; d < 8; ++d) {
            const int r = 64 + h*8 + d;
            float v0 = sBin[r], v1 = v0, v2 = v0;
            #pragma unroll
            for (int jj = 0; jj < 8; ++jj) {
                float4 w = W4[r*8 + jj];
                v0 = fmaf(f[0][4*jj+0], w.x, v0); v0 = fmaf(f[0][4*jj+1], w.y, v0);
                v0 = fmaf(f[0][4*jj+2], w.z, v0); v0 = fmaf(f[0][4*jj+3], w.w, v0);
                v1 = fmaf(f[1][4*jj+0], w.x, v1); v1 = fmaf(f[1][4*jj+1], w.y, v1);
                v1 = fmaf(f[1][4*jj+2], w.z, v1); v1 = fmaf(f[1][4*jj+3], w.w, v1);
                v2 = fmaf(f[2][4*jj+0], w.x, v2); v2 = fmaf(f[2][4*jj+1], w.y, v2);
                v2 = fmaf(f[2][4*jj+2], w.z, v2); v2 = fmaf(f[2][4*jj+3], w.w, v2);
            }
            float c0 = p[0][0]*v0 + p[0][1]*v1 + p[0][2]*v2;
            float c1 = p[1][0]*v0 + p[1][1]*v1 + p[1][2]*v2;
            float c2 = p[2][0]*v0 + p[2][1]*v1 + p[2][2]*v2;
            #pragma unroll
            for (int oo = 0; oo < 8; ++oo) {
                float4 w = WT4[(h*8 + d)*8 + oo];
                acc[0][4*oo+0] = fmaf(c0, w.x, acc[0][4*oo+0]);
                acc[0][4*oo+1] = fmaf(c0, w.y, acc[0][4*oo+1]);
                acc[0][4*oo+2] = fmaf(c0, w.z, acc[0][4*oo+2]);
                acc[0][4*oo+3] = fmaf(c0, w.w, acc[0][4*oo+3]);
                acc[1][4*oo+0] = fmaf(c1, w.x, acc[1][4*oo+0]);
                acc[1][4*oo+1] = fmaf(c1, w.y, acc[1][4*oo+1]);
                acc[1][4*oo+2] = fmaf(c1, w.z, acc[1][4*oo+2]);
                acc[1][4*oo+3] = fmaf(c1, w.w, acc[1][4*oo+3]);
                acc[2][4*oo+0] = fmaf(c2, w.x, acc[2][4*oo+0]);
                acc[2][4*oo+1] = fmaf(c2, w.y, acc[2][4*oo+1]);
                acc[2][4*oo+2] = fmaf(c2, w.z, acc[2][4*oo+2]);
                acc[2][4*oo+3] = fmaf(c2, w.w, acc[2][4*oo+3]);
            }
        }
    }

    // ---- epilogue ----
    float fused[32];
    #pragma unroll
    for (int o = 0; o < 32; ++o) fused[o] = 0.f;

    #pragma unroll
    for (int s = 0; s < 3; ++s) {
        const float ws = (s == 0) ? w0 : (s == 1) ? w1 : w2;
        float row[32];
        float mu = 0.f;
        #pragma unroll
        for (int o = 0; o < 32; ++o) {
            float a = acc[s][o] + sBout[o];
            row[o] = fmaf(a, ws, f[s][o]);
            mu += row[o];
        }
        mu *= (1.f/32.f);
        float var = 0.f;
        #pragma unroll
        for (int o = 0; o < 32; ++o) { float d = row[o] - mu; var = fmaf(d, d, var); }
        var *= (1.f/32.f);
        const float rs = rsqrtf(var + LN_EPS);
        #pragma unroll
        for (int o = 0; o < 32; ++o) {
            float y = (row[o] - mu) * rs * sGam[o] + sBet[o];
            fused[o] = fmaf(ws, y, fused[o]);
        }
    }

    float4* po = reinterpret_cast<float4*>(out + (size_t)b*32);
    #pragma unroll
    for (int q = 0; q < 8; ++q) {
        float4 r;
        r.x = fused[4*q+0]; r.y = fused[4*q+1]; r.z = fused[4*q+2]; r.w = fused[4*q+3];
        po[q] = r;
    }
}

// ---------------- fallback (ws too small): monolithic, self-detecting ----------------
__global__ __launch_bounds__(256, 1) void cmaf_mono(
    const u32* __restrict__ mwords,
    const float* __restrict__ metric, const float* __restrict__ logx,
    const float* __restrict__ trace,
    const float* __restrict__ Win, const float* __restrict__ bin,
    const float* __restrict__ Wout, const float* __restrict__ bout,
    const float* __restrict__ mw, const float* __restrict__ gam,
    const float* __restrict__ bet, float* __restrict__ out, int B, int nwords)
{
    __shared__ u32 sFlag;
    if (threadIdx.x == 0) sFlag = 0;
    __syncthreads();
    {
        int widx = blockIdx.x * 192 + (threadIdx.x % 192);
        if (widx >= nwords) widx = nwords - 1;
        if (mwords[widx] > 1u) sFlag = 1u;
    }
    __syncthreads();
    const bool bytePacked = (sFlag != 0);
    int b = blockIdx.x * 256 + threadIdx.x;
    if (b >= B) return;
    bool m0, m1, m2;
    if (bytePacked) {
        const u8* mb = (const u8*)mwords;
        m0 = mb[3*b+0] != 0; m1 = mb[3*b+1] != 0; m2 = mb[3*b+2] != 0;
    } else {
        const int* mi = (const int*)mwords;
        m0 = mi[3*b+0] != 0; m1 = mi[3*b+1] != 0; m2 = mi[3*b+2] != 0;
    }
    const int count = (int)m0 + (int)m1 + (int)m2;
    float4* po = reinterpret_cast<float4*>(out + (size_t)b*32);
    if (count <= 1) {
        const float* src = m0 ? metric : (m1 ? logx : (m2 ? trace : nullptr));
        if (src) {
            const float4* ps = reinterpret_cast<const float4*>(src + (size_t)b*32);
            #pragma unroll
            for (int k = 0; k < 8; ++k) po[k] = ps[k];
        } else {
            float4 z; z.x = z.y = z.z = z.w = 0.f;
            #pragma unroll
            for (int k = 0; k < 8; ++k) po[k] = z;
        }
        return;
    }
    float f[3][32];
    const float4* p0 = reinterpret_cast<const float4*>(metric + (size_t)b*32);
    const float4* p1 = reinterpret_cast<const float4*>(logx   + (size_t)b*32);
    const float4* p2 = reinterpret_cast<const float4*>(trace  + (size_t)b*32);
    #pragma unroll
    for (int q = 0; q < 8; ++q) {
        float4 a = p0[q];
        f[0][4*q+0]=a.x; f[0][4*q+1]=a.y; f[0][4*q+2]=a.z; f[0][4*q+3]=a.w;
        float4 c = p1[q];
        f[1][4*q+0]=c.x; f[1][4*q+1]=c.y; f[1][4*q+2]=c.z; f[1][4*q+3]=c.w;
        float4 d = p2[q];
        f[2][4*q+0]=d.x; f[2][4*q+1]=d.y; f[2][4*q+2]=d.z; f[2][4*q+3]=d.w;
    }
    float w0, w1, w2;
    {
        float l0 = m0 ? mw[0] : NEGV;
        float l1 = m1 ? mw[1] : NEGV;
        float l2 = m2 ? mw[2] : NEGV;
        float mx = fmaxf(l0, fmaxf(l1, l2));
        float e0 = __expf(l0 - mx), e1 = __expf(l1 - mx), e2 = __expf(l2 - mx);
        float inv = 1.f / (e0 + e1 + e2);
        w0 = e0*inv; w1 = e1*inv; w2 = e2*inv;
    }
    float acc[3][32];
    #pragma unroll
    for (int s = 0; s < 3; ++s)
        #pragma unroll
        for (int o = 0; o < 32; ++o) acc[s][o] = 0.f;
    const float scale = 0.35355339059327373f;
    #pragma unroll 1
    for (int h = 0; h < 4; ++h) {
        float kk[3][8], vv[3][8];
        #pragma unroll
        for (int s = 0; s < 3; ++s)
            #pragma unroll
            for (int d = 0; d < 8; ++d) {
                const int r = h*8 + d;
                float ak = bin[32 + r], av = bin[64 + r];
                const float* wkr = Win + (size_t)(32 + r)*32;
                const float* wvr = Win + (size_t)(64 + r)*32;
                #pragma unroll
                for (int j = 0; j < 32; ++j) {
                    float x = f[s][j];
                    ak = fmaf(x, wkr[j], ak); av = fmaf(x, wvr[j], av);
                }
                kk[s][d] = ak; vv[s][d] = av;
            }
        #pragma unroll
        for (int sq = 0; sq < 3; ++sq) {
            float s0 = 0.f, s1 = 0.f, s2 = 0.f;
            #pragma unroll
            for (int d = 0; d < 8; ++d) {
                const int r = h*8 + d;
                float aq = bin[r];
                const float* wqr = Win + (size_t)r*32;
                #pragma unroll
                for (int j = 0; j < 32; ++j) aq = fmaf(f[sq][j], wqr[j], aq);
                s0 = fmaf(aq, kk[0][d], s0);
                s1 = fmaf(aq, kk[1][d], s1);
                s2 = fmaf(aq, kk[2][d], s2);
            }
            s0 = m0 ? s0*scale : NEGV;
            s1 = m1 ? s1*scale : NEGV;
            s2 = m2 ? s2*scale : NEGV;
            float mx = fmaxf(s0, fmaxf(s1, s2));
            float e0 = __expf(s0 - mx), e1 = __expf(s1 - mx), e2 = __expf(s2 - mx);
            float inv = 1.f / (e0 + e1 + e2);
            e0 *= inv; e1 *= inv; e2 *= inv;
            #pragma unroll
            for (int d = 0; d < 8; ++d) {
                float c = e0*vv[0][d] + e1*vv[1][d] + e2*vv[2][d];
                const float* wc = Wout + h*8 + d;
                #pragma unroll
                for (int o = 0; o < 32; ++o)
                    acc[sq][o] = fmaf(c, wc[(size_t)o*32], acc[sq][o]);
            }
        }
    }
    float fused[32];
    #pragma unroll
    for (int o = 0; o < 32; ++o) fused[o] = 0.f;
    #pragma unroll
    for (int s = 0; s < 3; ++s) {
        const float ws = (s == 0) ? w0 : (s == 1) ? w1 : w2;
        float row[32];
        float mu = 0.f;
        #pragma unroll
        for (int o = 0; o < 32; ++o) {
            float a = acc[s][o] + bout[o];
            row[o] = fmaf(a, ws, f[s][o]);
            mu += row[o];
        }
        mu *= (1.f/32.f);
        float var = 0.f;
        #pragma unroll
        for (int o = 0; o < 32; ++o) { float d = row[o] - mu; var = fmaf(d, d, var); }
        var *= (1.f/32.f);
        const float rs = rsqrtf(var + LN_EPS);
        #pragma unroll
        for (int o = 0; o < 32; ++o) {
            float y = (row[o] - mu) * rs * gam[o] + bet[o];
            fused[o] = fmaf(ws, y, fused[o]);
        }
    }
    #pragma unroll
    for (int q = 0; q < 8; ++q) {
        float4 r;
        r.x = fused[4*q+0]; r.y = fused[4*q+1]; r.z = fused[4*q+2]; r.w = fused[4*q+3];
        po[q] = r;
    }
}

extern "C" void kernel_launch(void* const* d_in, const int* in_sizes, int n_in,
                              void* d_out, int out_size, void* d_ws, size_t ws_size,
                              hipStream_t stream) {
    const float* metric = (const float*)d_in[0];
    const float* logx   = (const float*)d_in[1];
    const float* trace  = (const float*)d_in[2];
    const u32*   masks  = (const u32*)d_in[3];
    const float* Win    = (const float*)d_in[4];
    const float* bin    = (const float*)d_in[5];
    const float* Wout   = (const float*)d_in[6];
    const float* bout   = (const float*)d_in[7];
    const float* mw     = (const float*)d_in[8];
    const float* gam    = (const float*)d_in[9];
    const float* bet    = (const float*)d_in[10];
    float* out = (float*)d_out;

    const int B = in_sizes[0] / 32;         // 262144
    const int grid = (B + 255) / 256;
    const int nwords = (3 * B) / 4;         // word count valid in byte encoding

    u32* ws        = (u32*)d_ws;
    u32* cnt       = ws;                    // [0]
    u32* heavyList = ws + 4;                // [4, 4+B)
    const size_t need = (size_t)(4 + (size_t)B) * 4;

    if (ws_size >= need) {
        hipMemsetAsync(d_ws, 0, 16, stream);
        hipLaunchKernelGGL(cmaf_classify_light, dim3(grid), dim3(256), 0, stream,
                           masks, cnt, heavyList, metric, logx, trace, out,
                           B, nwords);
        hipLaunchKernelGGL(cmaf_heavy, dim3(grid), dim3(256), 0, stream,
                           heavyList, cnt, metric, logx, trace,
                           Win, bin, Wout, bout, mw, gam, bet, out);
    } else {
        hipLaunchKernelGGL(cmaf_mono, dim3(grid), dim3(256), 0, stream,
                           masks, metric, logx, trace,
                           Win, bin, Wout, bout, mw, gam, bet, out, B, nwords);
    }
}